// Round 10
// baseline (253.779 us; speedup 1.0000x reference)
//
#include <hip/hip_runtime.h>

typedef float  f32x4  __attribute__((ext_vector_type(4)));
typedef __bf16 bf16x8 __attribute__((ext_vector_type(8)));
typedef __bf16 bf16x4 __attribute__((ext_vector_type(4)));

#define D_MODEL 512
#define SEQ     2048
#define BATCH   8
#define ROWS    (BATCH * SEQ)   // 16384

// async 16B global -> LDS (each lane deposits at lds_base + lane*16B)
#define ASYNC_COPY16(dst_lds, src_glb)                                          \
  __builtin_amdgcn_global_load_lds(                                             \
      (const __attribute__((address_space(1))) void*)(src_glb),                 \
      (__attribute__((address_space(3))) void*)(dst_lds), 16, 0, 0)

__device__ __forceinline__ bf16x8 cvt8(float4 a, float4 b) {
  bf16x8 o;
  o[0] = (__bf16)a.x; o[1] = (__bf16)a.y; o[2] = (__bf16)a.z; o[3] = (__bf16)a.w;
  o[4] = (__bf16)b.x; o[5] = (__bf16)b.y; o[6] = (__bf16)b.z; o[7] = (__bf16)b.w;
  return o;
}

// ------------------------------------------------------------ fused converts
// ROUND-10: G11/G13 rewrite — 8 elems/thread (2x float4 load -> one 16B
// bf16x8 store), grid-stride at 2048 blocks. Chunk map (1 chunk = 8 elems):
// [0,1048576) x1 | [1048576,2097152) x2 | [2097152,2621440) exp(posb)
// [2621440,2719744) Wq|Wk|Wv
__global__ __launch_bounds__(256) void cvt_all_kernel(
    const float* __restrict__ x1, const float* __restrict__ x2,
    const float* __restrict__ posb,
    const float* __restrict__ Wq, const float* __restrict__ Wk,
    const float* __restrict__ Wv,
    __bf16* __restrict__ x1b, __bf16* __restrict__ x2b,
    __bf16* __restrict__ expBb, __bf16* __restrict__ wb)
{
  const long long total = 2719744LL;
  for (long long c = (long long)blockIdx.x * 256 + threadIdx.x; c < total;
       c += (long long)gridDim.x * 256) {
    if (c < 2097152) {
      const bool two = (c >= 1048576);
      const long long off = (c - (two ? 1048576 : 0)) * 8;
      const float* src = two ? x2 : x1;
      __bf16* dst = two ? x2b : x1b;
      float4 a = *(const float4*)(src + off);
      float4 b = *(const float4*)(src + off + 4);
      *(bf16x8*)(dst + off) = cvt8(a, b);
    } else if (c < 2621440) {
      const long long off = (c - 2097152) * 8;
      float4 a = *(const float4*)(posb + off);
      float4 b = *(const float4*)(posb + off + 4);
      float4 ea = { __expf(a.x), __expf(a.y), __expf(a.z), __expf(a.w) };
      float4 eb = { __expf(b.x), __expf(b.y), __expf(b.z), __expf(b.w) };
      *(bf16x8*)(expBb + off) = cvt8(ea, eb);
    } else {
      const long long w = (c - 2621440) * 8;
      const long long nW = (long long)D_MODEL * D_MODEL;   // 262144
      const int sel = (int)(w / nW);
      const float* src = (sel == 0) ? Wq : (sel == 1) ? Wk : Wv;
      const long long so = w - (long long)sel * nW;
      float4 a = *(const float4*)(src + so);
      float4 b = *(const float4*)(src + so + 4);
      *(bf16x8*)(wb + w) = cvt8(a, b);
    }
  }
}

// ------------------------------------------------------------- q GEMM
// ROUND-10: 256(rows) x 256(d) tile on the einsum template (K=512, BK=64,
// 8 waves 2Mx4N, dbuf 128 KiB, spread staging). Grid (64,2) = 128 blocks.
// Halves x1b re-read (4x -> 2x). Shape+epilogue proven in round-3 tri_gemm.
__global__ __launch_bounds__(512) void q_gemm_kernel(
    const __bf16* __restrict__ x1b, const __bf16* __restrict__ wb,
    const float* __restrict__ bq, __bf16* __restrict__ sigq)
{
  extern __shared__ __align__(16) __bf16 smem[];  // A[2][16384] | B[2][16384]

  const int K = D_MODEL;
  const int tid  = threadIdx.x;
  const int wave = tid >> 6;
  const int lane = tid & 63;
  const int quad = lane >> 4;
  const int l16  = lane & 15;
  const int wm   = (wave >> 2) * 128;             // 2 wave-rows of 128
  const int wn   = (wave & 3) * 64;               // 4 wave-cols of 64
  const int m0   = blockIdx.x * 256;              // rows tile
  const int n0   = blockIdx.y * 256;              // d tile
  const int l8r  = lane >> 3;
  const int scol = ((lane & 7) ^ l8r) * 8;        // pre-swizzled global col

  const __bf16* gA = x1b + (long long)(m0 + wave * 8 + l8r) * K + scol;
  const __bf16* gB = wb  + (long long)(n0 + wave * 8 + l8r) * K + scol;
  __bf16* lA = smem +         (wave * 8) * 64;
  __bf16* lB = smem + 32768 + (wave * 8) * 64;

  f32x4 acc[8][4];
  #pragma unroll
  for (int i = 0; i < 8; ++i)
    #pragma unroll
    for (int j = 0; j < 4; ++j) acc[i][j] = (f32x4){0.f, 0.f, 0.f, 0.f};

  auto stage_pair = [&](int c, int k0, int i) {
    ASYNC_COPY16(lA + c * 16384 + i * 4096, gA + (long long)i * 64 * K + k0);
    ASYNC_COPY16(lB + c * 16384 + i * 4096, gB + (long long)i * 64 * K + k0);
  };

  #pragma unroll
  for (int i = 0; i < 4; ++i) stage_pair(0, 0, i);   // prologue

  const int s0 = ((quad    ) ^ (l16 & 7)) * 8;
  const int s1 = ((quad + 4) ^ (l16 & 7)) * 8;

  for (int t = 0; t < 8; ++t) {                   // K = 512 -> 8 tiles
    const int c = t & 1;
    asm volatile("s_waitcnt vmcnt(0)" ::: "memory");
    __builtin_amdgcn_s_barrier();
    __builtin_amdgcn_sched_barrier(0);

    const __bf16* Ac = smem +         c * 16384 + (wm + l16) * 64;
    const __bf16* Bc = smem + 32768 + c * 16384 + (wn + l16) * 64;
    const bool pf = (t + 1 < 8);
    const int k1 = (t + 1) * 64;

    bf16x8 bfr[4][2];
    #pragma unroll
    for (int q = 0; q < 4; ++q) {
      if (q == 0) {
        #pragma unroll
        for (int j = 0; j < 4; ++j) {
          bfr[j][0] = *(const bf16x8*)&Bc[j * 1024 + s0];
          bfr[j][1] = *(const bf16x8*)&Bc[j * 1024 + s1];
        }
      }
      bf16x8 af[2][2];
      #pragma unroll
      for (int ii = 0; ii < 2; ++ii) {
        af[ii][0] = *(const bf16x8*)&Ac[(q * 2 + ii) * 1024 + s0];
        af[ii][1] = *(const bf16x8*)&Ac[(q * 2 + ii) * 1024 + s1];
      }
      if (pf) {
        if (q == 0) { stage_pair(c ^ 1, k1, 0); stage_pair(c ^ 1, k1, 1); }
        else if (q == 1) { stage_pair(c ^ 1, k1, 2); stage_pair(c ^ 1, k1, 3); }
      }
      __builtin_amdgcn_s_barrier();
      asm volatile("s_waitcnt lgkmcnt(0)" ::: "memory");
      __builtin_amdgcn_sched_barrier(0);          // rule #18
      __builtin_amdgcn_s_setprio(1);
      #pragma unroll
      for (int kk = 0; kk < 2; ++kk)
        #pragma unroll
        for (int ii = 0; ii < 2; ++ii)
          #pragma unroll
          for (int j = 0; j < 4; ++j)
            acc[q * 2 + ii][j] = __builtin_amdgcn_mfma_f32_16x16x32_bf16(
                af[ii][kk], bfr[j][kk], acc[q * 2 + ii][j], 0, 0, 0);
      __builtin_amdgcn_s_setprio(0);
      __builtin_amdgcn_s_barrier();
    }
  }

  // epilogue (round-3 z=0 form): col = lane&15 (d), row = quad*4 + reg
  #pragma unroll
  for (int j = 0; j < 4; ++j) {
    const int col = n0 + wn + j * 16 + l16;
    const float bvv = bq[col];
    #pragma unroll
    for (int i = 0; i < 8; ++i) {
      #pragma unroll
      for (int r = 0; r < 4; ++r) {
        const int row = m0 + wm + i * 16 + quad * 4 + r;
        float x = acc[i][j][r] + bvv;
        sigq[(long long)row * D_MODEL + col] = (__bf16)(1.f / (1.f + __expf(-x)));
      }
    }
  }
}

// ------------------------------------------------------------- kv fused GEMM
// (round-8 proven) two sequential passes on the r3-q template; epilogue
// fuses exp(k+bk), ek*(v+bv), writes ekvT grouped directly.
__global__ __launch_bounds__(512) void kv_fused_kernel(
    const __bf16* __restrict__ x1b, const __bf16* __restrict__ x2b,
    const __bf16* __restrict__ wb,
    const float* __restrict__ bk, const float* __restrict__ bv,
    __bf16* __restrict__ ekvT)
{
  extern __shared__ __align__(16) __bf16 smem[];  // W[2][16384] | X[2][8192]

  const int K = D_MODEL;
  const int tid  = threadIdx.x;
  const int wave = tid >> 6;
  const int lane = tid & 63;
  const int quad = lane >> 4;
  const int l16  = lane & 15;
  const int wm   = (wave >> 1) * 64;   // 4 M-waves x 64 d
  const int wn   = (wave & 1) * 64;    // 2 N-waves x 64 rows
  const int F0   = blockIdx.y * 256;   // d tile
  const int L0   = blockIdx.x * 128;   // rows tile
  const int l8r  = lane >> 3;
  const int scol = ((lane & 7) ^ l8r) * 8;

  const __bf16* Wkb = wb + (long long)D_MODEL * D_MODEL;
  const __bf16* Wvb = wb + 2LL * D_MODEL * D_MODEL;

  const __bf16* gWk[4]; const __bf16* gWv[4];
  const __bf16* gX1[2]; const __bf16* gX2[2];
  #pragma unroll
  for (int i = 0; i < 4; ++i) {
    gWk[i] = Wkb + (long long)(F0 + i * 64 + wave * 8 + l8r) * K + scol;
    gWv[i] = Wvb + (long long)(F0 + i * 64 + wave * 8 + l8r) * K + scol;
  }
  #pragma unroll
  for (int i = 0; i < 2; ++i) {
    gX1[i] = x1b + (long long)(L0 + i * 64 + wave * 8 + l8r) * K + scol;
    gX2[i] = x2b + (long long)(L0 + i * 64 + wave * 8 + l8r) * K + scol;
  }

  f32x4 acck[4][4], accv[4][4];
  #pragma unroll
  for (int i = 0; i < 4; ++i)
    #pragma unroll
    for (int j = 0; j < 4; ++j) {
      acck[i][j] = (f32x4){0.f, 0.f, 0.f, 0.f};
      accv[i][j] = (f32x4){0.f, 0.f, 0.f, 0.f};
    }

  auto stgW = [&](int c, int i, const __bf16* p) {
    ASYNC_COPY16(smem + c * 16384 + (i * 64 + wave * 8) * 64, p);
  };
  auto stgX = [&](int c, int i, const __bf16* p) {
    ASYNC_COPY16(smem + 32768 + c * 8192 + (i * 64 + wave * 8) * 64, p);
  };

  // prologue: k-pass tile 0 into c=0 (6 loads)
  stgW(0, 0, gWk[0]); stgW(0, 1, gWk[1]); stgW(0, 2, gWk[2]); stgW(0, 3, gWk[3]);
  stgX(0, 0, gX1[0]); stgX(0, 1, gX1[1]);

  const int s0 = ((quad    ) ^ (l16 & 7)) * 8;
  const int s1 = ((quad + 4) ^ (l16 & 7)) * 8;

  auto pass = [&](f32x4 (&acc)[4][4], bool vpass) {
    for (int t = 0; t < 8; ++t) {
      const int c = t & 1;
      asm volatile("s_waitcnt vmcnt(0)" ::: "memory");
      __builtin_amdgcn_s_barrier();
      __builtin_amdgcn_sched_barrier(0);

      const __bf16* Ac = smem +         c * 16384 + (wm + l16) * 64;
      const __bf16* Bc = smem + 32768 + c * 8192  + (wn + l16) * 64;
      const bool nx = (t == 7);
      const bool pf = !(vpass && nx);
      const bool sv = vpass || nx;
      const int k1 = nx ? 0 : (t + 1) * 64;

      bf16x8 bfr[4][2];
      #pragma unroll
      for (int p = 0; p < 2; ++p) {
        if (p == 0) {
          #pragma unroll
          for (int j = 0; j < 4; ++j) {
            bfr[j][0] = *(const bf16x8*)&Bc[j * 1024 + s0];
            bfr[j][1] = *(const bf16x8*)&Bc[j * 1024 + s1];
          }
        }
        bf16x8 af[2][2];
        #pragma unroll
        for (int ii = 0; ii < 2; ++ii) {
          af[ii][0] = *(const bf16x8*)&Ac[(p * 2 + ii) * 1024 + s0];
          af[ii][1] = *(const bf16x8*)&Ac[(p * 2 + ii) * 1024 + s1];
        }
        if (pf) {
          if (p == 0) {
            stgW(c ^ 1, 0, (sv ? gWv[0] : gWk[0]) + k1);
            stgW(c ^ 1, 1, (sv ? gWv[1] : gWk[1]) + k1);
            stgX(c ^ 1, 0, (sv ? gX2[0] : gX1[0]) + k1);
          } else {
            stgW(c ^ 1, 2, (sv ? gWv[2] : gWk[2]) + k1);
            stgW(c ^ 1, 3, (sv ? gWv[3] : gWk[3]) + k1);
            stgX(c ^ 1, 1, (sv ? gX2[1] : gX1[1]) + k1);
          }
        }
        __builtin_amdgcn_s_barrier();
        asm volatile("s_waitcnt lgkmcnt(0)" ::: "memory");
        __builtin_amdgcn_sched_barrier(0);        // rule #18
        __builtin_amdgcn_s_setprio(1);
        #pragma unroll
        for (int kk = 0; kk < 2; ++kk)
          #pragma unroll
          for (int ii = 0; ii < 2; ++ii)
            #pragma unroll
            for (int j = 0; j < 4; ++j)
              acc[p * 2 + ii][j] = __builtin_amdgcn_mfma_f32_16x16x32_bf16(
                  af[ii][kk], bfr[j][kk], acc[p * 2 + ii][j], 0, 0, 0);
        __builtin_amdgcn_s_setprio(0);
        __builtin_amdgcn_s_barrier();
      }
    }
  };

  pass(acck, false);   // k = Wk x1^T
  pass(accv, true);    // v = Wv x2^T

  const int b   = L0 >> 11;
  const int sb  = L0 & 2047;
  __bf16* outb = ekvT + (long long)b * (2 * D_MODEL) * SEQ + sb;
  #pragma unroll
  for (int i = 0; i < 4; ++i) {
    #pragma unroll
    for (int r = 0; r < 4; ++r) {
      const int d = F0 + wm + i * 16 + quad * 4 + r;
      const float bkd = bk[d];
      const float bvd = bv[d];
      const int gr = ((d >> 5) << 6) + (d & 31);
      #pragma unroll
      for (int j = 0; j < 4; ++j) {
        const int ss = wn + j * 16 + l16;
        const float kkv = acck[i][j][r] + bkd;
        const float vvv = accv[i][j][r] + bvd;
        const float ekf = __expf(kkv);
        outb[(long long)gr * SEQ + ss]        = (__bf16)(ekf * vvv);
        outb[(long long)(gr + 32) * SEQ + ss] = (__bf16)ekf;
      }
    }
  }
}

// -------------------------------------------- einsum + final, fused epilogue
// stable anchor (round-4/8 structure): ~70us, MfmaUtil 37-39, 0 conflicts.
#define EBM 256
#define EBN 256
#define EBK 64
#define ENT (SEQ / EBK)   // 32

__global__ __launch_bounds__(512) void einsum_fused_kernel(
    const __bf16* __restrict__ A, const __bf16* __restrict__ BtAll,
    const __bf16* __restrict__ sigq, float* __restrict__ out)
{
  extern __shared__ __align__(16) __bf16 smem[];  // A[2][16384] | B[2][16384]

  const int b = blockIdx.z;
  const __bf16* Bt = BtAll + (long long)b * (2 * D_MODEL) * SEQ;

  const int tid  = threadIdx.x;
  const int wave = tid >> 6;
  const int lane = tid & 63;
  const int quad = lane >> 4;
  const int l16  = lane & 15;
  const int wm   = (wave >> 2) * 128;             // 2 wave-rows of 128
  const int wn   = (wave & 3) * 64;               // 4 wave-cols of 64
  const int m0   = blockIdx.x * EBM;
  const int n0   = blockIdx.y * EBN;
  const int l8r  = lane >> 3;
  const int scol = ((lane & 7) ^ l8r) * 8;        // pre-swizzled global col

  const __bf16* gA = A  + (long long)(m0 + wave * 8 + l8r) * SEQ + scol;
  const __bf16* gB = Bt + (long long)(n0 + wave * 8 + l8r) * SEQ + scol;
  __bf16* lA = smem +         (wave * 8) * 64;
  __bf16* lB = smem + 32768 + (wave * 8) * 64;

  f32x4 acc[8][4];
  #pragma unroll
  for (int i = 0; i < 8; ++i)
    #pragma unroll
    for (int j = 0; j < 4; ++j) acc[i][j] = (f32x4){0.f, 0.f, 0.f, 0.f};

  auto stage_pair = [&](int c, int k0, int i) {
    ASYNC_COPY16(lA + c * 16384 + i * 4096, gA + (long long)i * 64 * SEQ + k0);
    ASYNC_COPY16(lB + c * 16384 + i * 4096, gB + (long long)i * 64 * SEQ + k0);
  };

  #pragma unroll
  for (int i = 0; i < 4; ++i) stage_pair(0, 0, i);   // prologue burst (once)

  const int s0 = ((quad    ) ^ (l16 & 7)) * 8;    // k-slice 0 slot
  const int s1 = ((quad + 4) ^ (l16 & 7)) * 8;    // k-slice 1 slot

  for (int t = 0; t < ENT; ++t) {
    const int c = t & 1;
    asm volatile("s_waitcnt vmcnt(0)" ::: "memory");  // old loads only
    __builtin_amdgcn_s_barrier();                     // deposits visible
    __builtin_amdgcn_sched_barrier(0);

    const __bf16* Ac = smem +         c * 16384 + (wm + l16) * 64;
    const __bf16* Bc = smem + 32768 + c * 16384 + (wn + l16) * 64;
    const bool pf = (t + 1 < ENT);
    const int k1 = (t + 1) * EBK;

    bf16x8 bfr[4][2];                             // B frags resident all tile
    #pragma unroll
    for (int q = 0; q < 4; ++q) {                 // 4 sub-phases x 16 MFMA
      if (q == 0) {
        #pragma unroll
        for (int j = 0; j < 4; ++j) {
          bfr[j][0] = *(const bf16x8*)&Bc[j * 1024 + s0];
          bfr[j][1] = *(const bf16x8*)&Bc[j * 1024 + s1];
        }
      }
      bf16x8 af[2][2];
      #pragma unroll
      for (int ii = 0; ii < 2; ++ii) {
        af[ii][0] = *(const bf16x8*)&Ac[(q * 2 + ii) * 1024 + s0];
        af[ii][1] = *(const bf16x8*)&Ac[(q * 2 + ii) * 1024 + s1];
      }
      if (pf) {                                   // spread stage issue (m196)
        if (q == 0) { stage_pair(c ^ 1, k1, 0); stage_pair(c ^ 1, k1, 1); }
        else if (q == 1) { stage_pair(c ^ 1, k1, 2); stage_pair(c ^ 1, k1, 3); }
      }
      __builtin_amdgcn_s_barrier();
      asm volatile("s_waitcnt lgkmcnt(0)" ::: "memory");
      __builtin_amdgcn_sched_barrier(0);          // rule #18: pin MFMA after wait
      __builtin_amdgcn_s_setprio(1);
      #pragma unroll
      for (int kk = 0; kk < 2; ++kk)
        #pragma unroll
        for (int ii = 0; ii < 2; ++ii)
          #pragma unroll
          for (int j = 0; j < 4; ++j)
            acc[q * 2 + ii][j] = __builtin_amdgcn_mfma_f32_16x16x32_bf16(
                af[ii][kk], bfr[j][kk], acc[q * 2 + ii][j], 0, 0, 0);
      __builtin_amdgcn_s_setprio(0);
      __builtin_amdgcn_s_barrier();
    }
  }

  // epilogue: C/D layout col = lane&15, row = quad*4 + reg
  const int g = (n0 + wn) >> 6;                   // channel group 0..15
  #pragma unroll
  for (int j = 0; j < 2; ++j) {
    const int d = g * 32 + j * 16 + l16;
    #pragma unroll
    for (int i = 0; i < 8; ++i) {
      #pragma unroll
      for (int r = 0; r < 4; ++r) {
        const int row = m0 + wm + i * 16 + quad * 4 + r;
        const long long off = ((long long)b * SEQ + row) * D_MODEL + d;
        const float num = acc[i][j][r];
        const float den = acc[i][j + 2][r];
        out[off] = (float)sigq[off] * (num / den);
      }
    }
  }
}

// ---------------------------------------------------------------- launch
extern "C" void kernel_launch(void* const* d_in, const int* in_sizes, int n_in,
                              void* d_out, int out_size, void* d_ws, size_t ws_size,
                              hipStream_t stream) {
  const float* inputs1 = (const float*)d_in[0];
  const float* inputs2 = (const float*)d_in[1];
  const float* Wq = (const float*)d_in[2];
  const float* bq = (const float*)d_in[3];
  const float* Wk = (const float*)d_in[4];
  const float* bk = (const float*)d_in[5];
  const float* Wv = (const float*)d_in[6];
  const float* bv = (const float*)d_in[7];
  const float* posb = (const float*)d_in[8];
  float* out = (float*)d_out;

  // workspace layout
  char* ws = (char*)d_ws;
  const long long szX  = (long long)ROWS * D_MODEL * 2;            // 16.78 MB
  const long long szW  = (long long)D_MODEL * D_MODEL * 2;         // 0.52 MB
  const long long szEB = (long long)SEQ * SEQ * 2;                 // 8.39 MB
  const long long szT  = (long long)BATCH * 2 * D_MODEL * SEQ * 2; // 33.55 MB
  __bf16* x1b   = (__bf16*)(ws);                 ws += szX;
  __bf16* x2b   = (__bf16*)(ws);                 ws += szX;
  __bf16* wb    = (__bf16*)(ws);                 ws += 3 * szW;
  __bf16* expBb = (__bf16*)(ws);                 ws += szEB;
  __bf16* sigq  = (__bf16*)(ws);                 ws += szX;
  __bf16* ekvT  = (__bf16*)(ws);                 ws += szT;

  // one-time: allow big dynamic LDS for the tile kernels
  static bool attr_done = false;
  if (!attr_done) {
    hipFuncSetAttribute((const void*)einsum_fused_kernel,
                        hipFuncAttributeMaxDynamicSharedMemorySize, 131072);
    hipFuncSetAttribute((const void*)q_gemm_kernel,
                        hipFuncAttributeMaxDynamicSharedMemorySize, 131072);
    hipFuncSetAttribute((const void*)kv_fused_kernel,
                        hipFuncAttributeMaxDynamicSharedMemorySize, 98304);
    attr_done = true;
  }

  // 1) all converts: grid-stride, 16B stores (G11/G13)
  cvt_all_kernel<<<2048, 256, 0, stream>>>(inputs1, inputs2, posb,
                                           Wq, Wk, Wv,
                                           x1b, x2b, expBb, wb);

  // 2a) q GEMM: 256x256 tiles, grid (64,2) = 128 blocks (x1b read 2x not 4x)
  {
    dim3 g(ROWS / 256, D_MODEL / 256);
    q_gemm_kernel<<<g, 512, 131072, stream>>>(x1b, wb, bq, sigq);
  }

  // 2b) kv fused GEMM + exp combine: two proven-schedule passes, grid 256
  {
    dim3 g(ROWS / 128, D_MODEL / 256);
    kv_fused_kernel<<<g, 512, 98304, stream>>>(x1b, x2b, wb, bk, bv, ekvT);
  }

  // 3) einsum + final fused: round-4 structure (BK=64, 4-phase, dbuf-2)
  {
    dim3 g(SEQ / EBM, (2 * D_MODEL) / EBN, BATCH);
    einsum_fused_kernel<<<g, 512, 131072, stream>>>(expBb, ekvT, sigq, out);
  }
}

// Round 11
// 239.068 us; speedup vs baseline: 1.0615x; 1.0615x over previous
//
#include <hip/hip_runtime.h>

typedef float  f32x4  __attribute__((ext_vector_type(4)));
typedef __bf16 bf16x8 __attribute__((ext_vector_type(8)));
typedef __bf16 bf16x4 __attribute__((ext_vector_type(4)));

#define D_MODEL 512
#define SEQ     2048
#define BATCH   8
#define ROWS    (BATCH * SEQ)   // 16384

// async 16B global -> LDS (each lane deposits at lds_base + lane*16B)
#define ASYNC_COPY16(dst_lds, src_glb)                                          \
  __builtin_amdgcn_global_load_lds(                                             \
      (const __attribute__((address_space(1))) void*)(src_glb),                 \
      (__attribute__((address_space(3))) void*)(dst_lds), 16, 0, 0)

__device__ __forceinline__ bf16x8 cvt8(float4 a, float4 b) {
  bf16x8 o;
  o[0] = (__bf16)a.x; o[1] = (__bf16)a.y; o[2] = (__bf16)a.z; o[3] = (__bf16)a.w;
  o[4] = (__bf16)b.x; o[5] = (__bf16)b.y; o[6] = (__bf16)b.z; o[7] = (__bf16)b.w;
  return o;
}

// ------------------------------------------------------------ fused converts
// G11/G13: 8 elems/thread (2x float4 -> one 16B bf16x8 store), grid-stride.
__global__ __launch_bounds__(256) void cvt_all_kernel(
    const float* __restrict__ x1, const float* __restrict__ x2,
    const float* __restrict__ posb,
    const float* __restrict__ Wq, const float* __restrict__ Wk,
    const float* __restrict__ Wv,
    __bf16* __restrict__ x1b, __bf16* __restrict__ x2b,
    __bf16* __restrict__ expBb, __bf16* __restrict__ wb)
{
  const long long total = 2719744LL;
  for (long long c = (long long)blockIdx.x * 256 + threadIdx.x; c < total;
       c += (long long)gridDim.x * 256) {
    if (c < 2097152) {
      const bool two = (c >= 1048576);
      const long long off = (c - (two ? 1048576 : 0)) * 8;
      const float* src = two ? x2 : x1;
      __bf16* dst = two ? x2b : x1b;
      float4 a = *(const float4*)(src + off);
      float4 b = *(const float4*)(src + off + 4);
      *(bf16x8*)(dst + off) = cvt8(a, b);
    } else if (c < 2621440) {
      const long long off = (c - 2097152) * 8;
      float4 a = *(const float4*)(posb + off);
      float4 b = *(const float4*)(posb + off + 4);
      float4 ea = { __expf(a.x), __expf(a.y), __expf(a.z), __expf(a.w) };
      float4 eb = { __expf(b.x), __expf(b.y), __expf(b.z), __expf(b.w) };
      *(bf16x8*)(expBb + off) = cvt8(ea, eb);
    } else {
      const long long w = (c - 2621440) * 8;
      const long long nW = (long long)D_MODEL * D_MODEL;   // 262144
      const int sel = (int)(w / nW);
      const float* src = (sel == 0) ? Wq : (sel == 1) ? Wk : Wv;
      const long long so = w - (long long)sel * nW;
      float4 a = *(const float4*)(src + so);
      float4 b = *(const float4*)(src + so + 4);
      *(bf16x8*)(wb + w) = cvt8(a, b);
    }
  }
}

// ------------------------------------------------------------- q + kv merged
// ROUND-11: one launch, 512 blocks = 2 full chip waves. z=0: kv (r8 body,
// grid 128x2); z=1: q (r8 body, 256x128 tiles, flat remap to 64x4).
// Bodies byte-identical to the round-8 proven kernels.
__global__ __launch_bounds__(512) void qkv_kernel(
    const __bf16* __restrict__ x1b, const __bf16* __restrict__ x2b,
    const __bf16* __restrict__ wb,
    const float* __restrict__ bq, const float* __restrict__ bk,
    const float* __restrict__ bv,
    __bf16* __restrict__ sigq, __bf16* __restrict__ ekvT)
{
  extern __shared__ __align__(16) __bf16 smem[];  // 96 KiB both branches

  const int K = D_MODEL;
  const int tid  = threadIdx.x;
  const int wave = tid >> 6;
  const int lane = tid & 63;
  const int quad = lane >> 4;
  const int l16  = lane & 15;
  const int l8r  = lane >> 3;
  const int scol = ((lane & 7) ^ l8r) * 8;        // pre-swizzled global col
  const int s0 = ((quad    ) ^ (l16 & 7)) * 8;
  const int s1 = ((quad + 4) ^ (l16 & 7)) * 8;

  if (blockIdx.z == 1) {
    // ---------------- q: sigmoid(x1*Wq^T + bq) -> sigq [rows][d]
    const int flat = blockIdx.y * 128 + blockIdx.x;   // 0..255
    const int m0   = (flat & 63) * 256;               // rows tile
    const int n0   = (flat >> 6) * 128;               // d tile
    const int wm   = (wave >> 1) * 64;   // 4 M-waves x 64 rows
    const int wn   = (wave & 1) * 64;    // 2 N-waves x 64 d

    const __bf16* ga[4]; const __bf16* gb[2];
    #pragma unroll
    for (int i = 0; i < 4; ++i)
      ga[i] = x1b + (long long)(m0 + i * 64 + wave * 8 + l8r) * K + scol;
    #pragma unroll
    for (int i = 0; i < 2; ++i)
      gb[i] = wb + (long long)(n0 + i * 64 + wave * 8 + l8r) * K + scol;

    f32x4 acc[4][4];
    #pragma unroll
    for (int i = 0; i < 4; ++i)
      #pragma unroll
      for (int j = 0; j < 4; ++j) acc[i][j] = (f32x4){0.f, 0.f, 0.f, 0.f};

    auto stageA2 = [&](int c, int k0, int i0) {
      ASYNC_COPY16(smem + c * 16384 + (i0 * 64 + wave * 8) * 64, ga[i0] + k0);
      ASYNC_COPY16(smem + c * 16384 + ((i0 + 1) * 64 + wave * 8) * 64, ga[i0 + 1] + k0);
    };
    auto stageB1 = [&](int c, int k0, int i) {
      ASYNC_COPY16(smem + 32768 + c * 8192 + (i * 64 + wave * 8) * 64, gb[i] + k0);
    };

    stageA2(0, 0, 0); stageA2(0, 0, 2);
    stageB1(0, 0, 0); stageB1(0, 0, 1);             // prologue (6 loads)

    for (int t = 0; t < 8; ++t) {
      const int c = t & 1;
      asm volatile("s_waitcnt vmcnt(0)" ::: "memory");
      __builtin_amdgcn_s_barrier();
      __builtin_amdgcn_sched_barrier(0);

      const __bf16* Ac = smem +         c * 16384 + (wm + l16) * 64;
      const __bf16* Bc = smem + 32768 + c * 8192  + (wn + l16) * 64;
      const bool pf = (t + 1 < 8);
      const int k1 = (t + 1) * 64;

      bf16x8 bfr[4][2];
      #pragma unroll
      for (int p = 0; p < 2; ++p) {
        if (p == 0) {
          #pragma unroll
          for (int j = 0; j < 4; ++j) {
            bfr[j][0] = *(const bf16x8*)&Bc[j * 1024 + s0];
            bfr[j][1] = *(const bf16x8*)&Bc[j * 1024 + s1];
          }
        }
        bf16x8 af[2][2];
        #pragma unroll
        for (int ii = 0; ii < 2; ++ii) {
          af[ii][0] = *(const bf16x8*)&Ac[(p * 2 + ii) * 1024 + s0];
          af[ii][1] = *(const bf16x8*)&Ac[(p * 2 + ii) * 1024 + s1];
        }
        if (pf) {
          if (p == 0) { stageA2(c ^ 1, k1, 0); stageB1(c ^ 1, k1, 0); }
          else        { stageA2(c ^ 1, k1, 2); stageB1(c ^ 1, k1, 1); }
        }
        __builtin_amdgcn_s_barrier();
        asm volatile("s_waitcnt lgkmcnt(0)" ::: "memory");
        __builtin_amdgcn_sched_barrier(0);        // rule #18
        __builtin_amdgcn_s_setprio(1);
        #pragma unroll
        for (int kk = 0; kk < 2; ++kk)
          #pragma unroll
          for (int ii = 0; ii < 2; ++ii)
            #pragma unroll
            for (int j = 0; j < 4; ++j)
              acc[p * 2 + ii][j] = __builtin_amdgcn_mfma_f32_16x16x32_bf16(
                  af[ii][kk], bfr[j][kk], acc[p * 2 + ii][j], 0, 0, 0);
        __builtin_amdgcn_s_setprio(0);
        __builtin_amdgcn_s_barrier();
      }
    }

    #pragma unroll
    for (int j = 0; j < 4; ++j) {
      const int col = n0 + wn + j * 16 + l16;
      const float bvv = bq[col];
      #pragma unroll
      for (int i = 0; i < 4; ++i) {
        #pragma unroll
        for (int r = 0; r < 4; ++r) {
          const int row = m0 + wm + i * 16 + quad * 4 + r;
          float x = acc[i][j][r] + bvv;
          sigq[(long long)row * D_MODEL + col] = (__bf16)(1.f / (1.f + __expf(-x)));
        }
      }
    }
  } else {
    // ---------------- kv: two proven-schedule passes; epilogue fuses
    // exp(k+bk), ek*(v+bv), writes ekvT grouped directly.
    const int wm   = (wave >> 1) * 64;   // 4 M-waves x 64 d
    const int wn   = (wave & 1) * 64;    // 2 N-waves x 64 rows
    const int F0   = blockIdx.y * 256;   // d tile
    const int L0   = blockIdx.x * 128;   // rows tile

    const __bf16* Wkb = wb + (long long)D_MODEL * D_MODEL;
    const __bf16* Wvb = wb + 2LL * D_MODEL * D_MODEL;

    const __bf16* gWk[4]; const __bf16* gWv[4];
    const __bf16* gX1[2]; const __bf16* gX2[2];
    #pragma unroll
    for (int i = 0; i < 4; ++i) {
      gWk[i] = Wkb + (long long)(F0 + i * 64 + wave * 8 + l8r) * K + scol;
      gWv[i] = Wvb + (long long)(F0 + i * 64 + wave * 8 + l8r) * K + scol;
    }
    #pragma unroll
    for (int i = 0; i < 2; ++i) {
      gX1[i] = x1b + (long long)(L0 + i * 64 + wave * 8 + l8r) * K + scol;
      gX2[i] = x2b + (long long)(L0 + i * 64 + wave * 8 + l8r) * K + scol;
    }

    f32x4 acck[4][4], accv[4][4];
    #pragma unroll
    for (int i = 0; i < 4; ++i)
      #pragma unroll
      for (int j = 0; j < 4; ++j) {
        acck[i][j] = (f32x4){0.f, 0.f, 0.f, 0.f};
        accv[i][j] = (f32x4){0.f, 0.f, 0.f, 0.f};
      }

    auto stgW = [&](int c, int i, const __bf16* p) {
      ASYNC_COPY16(smem + c * 16384 + (i * 64 + wave * 8) * 64, p);
    };
    auto stgX = [&](int c, int i, const __bf16* p) {
      ASYNC_COPY16(smem + 32768 + c * 8192 + (i * 64 + wave * 8) * 64, p);
    };

    stgW(0, 0, gWk[0]); stgW(0, 1, gWk[1]); stgW(0, 2, gWk[2]); stgW(0, 3, gWk[3]);
    stgX(0, 0, gX1[0]); stgX(0, 1, gX1[1]);        // prologue (6 loads)

    auto pass = [&](f32x4 (&acc)[4][4], bool vpass) {
      for (int t = 0; t < 8; ++t) {
        const int c = t & 1;
        asm volatile("s_waitcnt vmcnt(0)" ::: "memory");
        __builtin_amdgcn_s_barrier();
        __builtin_amdgcn_sched_barrier(0);

        const __bf16* Ac = smem +         c * 16384 + (wm + l16) * 64;
        const __bf16* Bc = smem + 32768 + c * 8192  + (wn + l16) * 64;
        const bool nx = (t == 7);
        const bool pf = !(vpass && nx);
        const bool sv = vpass || nx;
        const int k1 = nx ? 0 : (t + 1) * 64;

        bf16x8 bfr[4][2];
        #pragma unroll
        for (int p = 0; p < 2; ++p) {
          if (p == 0) {
            #pragma unroll
            for (int j = 0; j < 4; ++j) {
              bfr[j][0] = *(const bf16x8*)&Bc[j * 1024 + s0];
              bfr[j][1] = *(const bf16x8*)&Bc[j * 1024 + s1];
            }
          }
          bf16x8 af[2][2];
          #pragma unroll
          for (int ii = 0; ii < 2; ++ii) {
            af[ii][0] = *(const bf16x8*)&Ac[(p * 2 + ii) * 1024 + s0];
            af[ii][1] = *(const bf16x8*)&Ac[(p * 2 + ii) * 1024 + s1];
          }
          if (pf) {
            if (p == 0) {
              stgW(c ^ 1, 0, (sv ? gWv[0] : gWk[0]) + k1);
              stgW(c ^ 1, 1, (sv ? gWv[1] : gWk[1]) + k1);
              stgX(c ^ 1, 0, (sv ? gX2[0] : gX1[0]) + k1);
            } else {
              stgW(c ^ 1, 2, (sv ? gWv[2] : gWk[2]) + k1);
              stgW(c ^ 1, 3, (sv ? gWv[3] : gWk[3]) + k1);
              stgX(c ^ 1, 1, (sv ? gX2[1] : gX1[1]) + k1);
            }
          }
          __builtin_amdgcn_s_barrier();
          asm volatile("s_waitcnt lgkmcnt(0)" ::: "memory");
          __builtin_amdgcn_sched_barrier(0);      // rule #18
          __builtin_amdgcn_s_setprio(1);
          #pragma unroll
          for (int kk = 0; kk < 2; ++kk)
            #pragma unroll
            for (int ii = 0; ii < 2; ++ii)
              #pragma unroll
              for (int j = 0; j < 4; ++j)
                acc[p * 2 + ii][j] = __builtin_amdgcn_mfma_f32_16x16x32_bf16(
                    af[ii][kk], bfr[j][kk], acc[p * 2 + ii][j], 0, 0, 0);
          __builtin_amdgcn_s_setprio(0);
          __builtin_amdgcn_s_barrier();
        }
      }
    };

    pass(acck, false);   // k = Wk x1^T
    pass(accv, true);    // v = Wv x2^T

    const int b   = L0 >> 11;
    const int sb  = L0 & 2047;
    __bf16* outb = ekvT + (long long)b * (2 * D_MODEL) * SEQ + sb;
    #pragma unroll
    for (int i = 0; i < 4; ++i) {
      #pragma unroll
      for (int r = 0; r < 4; ++r) {
        const int d = F0 + wm + i * 16 + quad * 4 + r;
        const float bkd = bk[d];
        const float bvd = bv[d];
        const int gr = ((d >> 5) << 6) + (d & 31);
        #pragma unroll
        for (int j = 0; j < 4; ++j) {
          const int ss = wn + j * 16 + l16;
          const float kkv = acck[i][j][r] + bkd;
          const float vvv = accv[i][j][r] + bvd;
          const float ekf = __expf(kkv);
          outb[(long long)gr * SEQ + ss]        = (__bf16)(ekf * vvv);
          outb[(long long)(gr + 32) * SEQ + ss] = (__bf16)ekf;
        }
      }
    }
  }
}

// -------------------------------------------- einsum + final, fused epilogue
// stable anchor (round-4/8 structure): ~70us, MfmaUtil 37-39, 0 conflicts.
#define EBM 256
#define EBN 256
#define EBK 64
#define ENT (SEQ / EBK)   // 32

__global__ __launch_bounds__(512) void einsum_fused_kernel(
    const __bf16* __restrict__ A, const __bf16* __restrict__ BtAll,
    const __bf16* __restrict__ sigq, float* __restrict__ out)
{
  extern __shared__ __align__(16) __bf16 smem[];  // A[2][16384] | B[2][16384]

  const int b = blockIdx.z;
  const __bf16* Bt = BtAll + (long long)b * (2 * D_MODEL) * SEQ;

  const int tid  = threadIdx.x;
  const int wave = tid >> 6;
  const int lane = tid & 63;
  const int quad = lane >> 4;
  const int l16  = lane & 15;
  const int wm   = (wave >> 2) * 128;             // 2 wave-rows of 128
  const int wn   = (wave & 3) * 64;               // 4 wave-cols of 64
  const int m0   = blockIdx.x * EBM;
  const int n0   = blockIdx.y * EBN;
  const int l8r  = lane >> 3;
  const int scol = ((lane & 7) ^ l8r) * 8;        // pre-swizzled global col

  const __bf16* gA = A  + (long long)(m0 + wave * 8 + l8r) * SEQ + scol;
  const __bf16* gB = Bt + (long long)(n0 + wave * 8 + l8r) * SEQ + scol;
  __bf16* lA = smem +         (wave * 8) * 64;
  __bf16* lB = smem + 32768 + (wave * 8) * 64;

  f32x4 acc[8][4];
  #pragma unroll
  for (int i = 0; i < 8; ++i)
    #pragma unroll
    for (int j = 0; j < 4; ++j) acc[i][j] = (f32x4){0.f, 0.f, 0.f, 0.f};

  auto stage_pair = [&](int c, int k0, int i) {
    ASYNC_COPY16(lA + c * 16384 + i * 4096, gA + (long long)i * 64 * SEQ + k0);
    ASYNC_COPY16(lB + c * 16384 + i * 4096, gB + (long long)i * 64 * SEQ + k0);
  };

  #pragma unroll
  for (int i = 0; i < 4; ++i) stage_pair(0, 0, i);   // prologue burst (once)

  const int s0 = ((quad    ) ^ (l16 & 7)) * 8;    // k-slice 0 slot
  const int s1 = ((quad + 4) ^ (l16 & 7)) * 8;    // k-slice 1 slot

  for (int t = 0; t < ENT; ++t) {
    const int c = t & 1;
    asm volatile("s_waitcnt vmcnt(0)" ::: "memory");  // old loads only
    __builtin_amdgcn_s_barrier();                     // deposits visible
    __builtin_amdgcn_sched_barrier(0);

    const __bf16* Ac = smem +         c * 16384 + (wm + l16) * 64;
    const __bf16* Bc = smem + 32768 + c * 16384 + (wn + l16) * 64;
    const bool pf = (t + 1 < ENT);
    const int k1 = (t + 1) * EBK;

    bf16x8 bfr[4][2];                             // B frags resident all tile
    #pragma unroll
    for (int q = 0; q < 4; ++q) {                 // 4 sub-phases x 16 MFMA
      if (q == 0) {
        #pragma unroll
        for (int j = 0; j < 4; ++j) {
          bfr[j][0] = *(const bf16x8*)&Bc[j * 1024 + s0];
          bfr[j][1] = *(const bf16x8*)&Bc[j * 1024 + s1];
        }
      }
      bf16x8 af[2][2];
      #pragma unroll
      for (int ii = 0; ii < 2; ++ii) {
        af[ii][0] = *(const bf16x8*)&Ac[(q * 2 + ii) * 1024 + s0];
        af[ii][1] = *(const bf16x8*)&Ac[(q * 2 + ii) * 1024 + s1];
      }
      if (pf) {                                   // spread stage issue (m196)
        if (q == 0) { stage_pair(c ^ 1, k1, 0); stage_pair(c ^ 1, k1, 1); }
        else if (q == 1) { stage_pair(c ^ 1, k1, 2); stage_pair(c ^ 1, k1, 3); }
      }
      __builtin_amdgcn_s_barrier();
      asm volatile("s_waitcnt lgkmcnt(0)" ::: "memory");
      __builtin_amdgcn_sched_barrier(0);          // rule #18: pin MFMA after wait
      __builtin_amdgcn_s_setprio(1);
      #pragma unroll
      for (int kk = 0; kk < 2; ++kk)
        #pragma unroll
        for (int ii = 0; ii < 2; ++ii)
          #pragma unroll
          for (int j = 0; j < 4; ++j)
            acc[q * 2 + ii][j] = __builtin_amdgcn_mfma_f32_16x16x32_bf16(
                af[ii][kk], bfr[j][kk], acc[q * 2 + ii][j], 0, 0, 0);
      __builtin_amdgcn_s_setprio(0);
      __builtin_amdgcn_s_barrier();
    }
  }

  // epilogue: C/D layout col = lane&15, row = quad*4 + reg
  const int g = (n0 + wn) >> 6;                   // channel group 0..15
  #pragma unroll
  for (int j = 0; j < 2; ++j) {
    const int d = g * 32 + j * 16 + l16;
    #pragma unroll
    for (int i = 0; i < 8; ++i) {
      #pragma unroll
      for (int r = 0; r < 4; ++r) {
        const int row = m0 + wm + i * 16 + quad * 4 + r;
        const long long off = ((long long)b * SEQ + row) * D_MODEL + d;
        const float num = acc[i][j][r];
        const float den = acc[i][j + 2][r];
        out[off] = (float)sigq[off] * (num / den);
      }
    }
  }
}

// ---------------------------------------------------------------- launch
extern "C" void kernel_launch(void* const* d_in, const int* in_sizes, int n_in,
                              void* d_out, int out_size, void* d_ws, size_t ws_size,
                              hipStream_t stream) {
  const float* inputs1 = (const float*)d_in[0];
  const float* inputs2 = (const float*)d_in[1];
  const float* Wq = (const float*)d_in[2];
  const float* bq = (const float*)d_in[3];
  const float* Wk = (const float*)d_in[4];
  const float* bk = (const float*)d_in[5];
  const float* Wv = (const float*)d_in[6];
  const float* bv = (const float*)d_in[7];
  const float* posb = (const float*)d_in[8];
  float* out = (float*)d_out;

  // workspace layout
  char* ws = (char*)d_ws;
  const long long szX  = (long long)ROWS * D_MODEL * 2;            // 16.78 MB
  const long long szW  = (long long)D_MODEL * D_MODEL * 2;         // 0.52 MB
  const long long szEB = (long long)SEQ * SEQ * 2;                 // 8.39 MB
  const long long szT  = (long long)BATCH * 2 * D_MODEL * SEQ * 2; // 33.55 MB
  __bf16* x1b   = (__bf16*)(ws);                 ws += szX;
  __bf16* x2b   = (__bf16*)(ws);                 ws += szX;
  __bf16* wb    = (__bf16*)(ws);                 ws += 3 * szW;
  __bf16* expBb = (__bf16*)(ws);                 ws += szEB;
  __bf16* sigq  = (__bf16*)(ws);                 ws += szX;
  __bf16* ekvT  = (__bf16*)(ws);                 ws += szT;

  // one-time: allow big dynamic LDS for the tile kernels
  static bool attr_done = false;
  if (!attr_done) {
    hipFuncSetAttribute((const void*)einsum_fused_kernel,
                        hipFuncAttributeMaxDynamicSharedMemorySize, 131072);
    hipFuncSetAttribute((const void*)qkv_kernel,
                        hipFuncAttributeMaxDynamicSharedMemorySize, 98304);
    attr_done = true;
  }

  // 1) all converts: grid-stride, 16B stores (G11/G13)
  cvt_all_kernel<<<2048, 256, 0, stream>>>(inputs1, inputs2, posb,
                                           Wq, Wk, Wv,
                                           x1b, x2b, expBb, wb);

  // 2) q + kv in ONE launch: 512 blocks = 2 full chip waves
  //    z=0: kv (128x2 tiles of 256d x 128rows); z=1: q (256 blocks, 256x128)
  {
    dim3 g(128, 2, 2);
    qkv_kernel<<<g, 512, 98304, stream>>>(x1b, x2b, wb, bq, bk, bv,
                                          sigq, ekvT);
  }

  // 3) einsum + final fused: round-4 structure (BK=64, 4-phase, dbuf-2)
  {
    dim3 g(SEQ / EBM, (2 * D_MODEL) / EBN, BATCH);
    einsum_fused_kernel<<<g, 512, 131072, stream>>>(expBb, ekvT, sigq, out);
  }
}